// Round 1
// baseline (3253.054 us; speedup 1.0000x reference)
//
#include <hip/hip_runtime.h>
#include <hip/hip_bf16.h>
#include <math.h>

#define T_SEQ 2048
#define D_MODEL 1024
#define N_HEADS 16
#define HEAD_DIM 64
#define FFN_DIM 4096

// ---------------- LayerNorm: one block per row ----------------
__global__ __launch_bounds__(256) void ln_kernel(
    const float* __restrict__ x, const float* __restrict__ g,
    const float* __restrict__ b, float* __restrict__ y, int D) {
  int row = blockIdx.x;
  const float* xr = x + (size_t)row * D;
  float* yr = y + (size_t)row * D;
  int tid = threadIdx.x;
  int lid = tid & 63, wid = tid >> 6;
  __shared__ float red[8];

  float sum = 0.f;
  for (int i = tid; i < D; i += 256) sum += xr[i];
  for (int o = 32; o > 0; o >>= 1) sum += __shfl_down(sum, o, 64);
  if (lid == 0) red[wid] = sum;
  __syncthreads();
  if (tid == 0) { float t = 0; for (int i = 0; i < 4; i++) t += red[i]; red[0] = t; }
  __syncthreads();
  float mu = red[0] / D;
  __syncthreads();

  float vs = 0.f;
  for (int i = tid; i < D; i += 256) { float d = xr[i] - mu; vs += d * d; }
  for (int o = 32; o > 0; o >>= 1) vs += __shfl_down(vs, o, 64);
  if (lid == 0) red[wid] = vs;
  __syncthreads();
  if (tid == 0) { float t = 0; for (int i = 0; i < 4; i++) t += red[i]; red[0] = t; }
  __syncthreads();
  float rstd = rsqrtf(red[0] / D + 1e-5f);

  for (int i = tid; i < D; i += 256)
    yr[i] = (xr[i] - mu) * rstd * g[i] + b[i];
}

// ---------------- GEMM: C = A(MxK) @ B(KxN) + bias, fused epilogue --------
// mode 0: bias only; mode 1: bias + exact GELU; mode 2: bias + residual add
#define BM 64
#define BN 64
#define BK 16
__global__ __launch_bounds__(256) void gemm_kernel(
    const float* __restrict__ A, const float* __restrict__ B,
    const float* __restrict__ bias, const float* __restrict__ res,
    float* __restrict__ C, int M, int N, int Kd, int mode) {
  __shared__ float As[BK][BM + 1];
  __shared__ float Bs[BK][BN + 1];
  int tid = threadIdx.x;
  int bm = blockIdx.y, bn = blockIdx.x;
  int tx = tid & 15, ty = tid >> 4;
  float acc[4][4] = {};

  for (int k0 = 0; k0 < Kd; k0 += BK) {
#pragma unroll
    for (int i = 0; i < 4; i++) {  // A tile 64x16 -> As[k][m]
      int linear = tid + i * 256;
      int r = linear >> 4, c = linear & 15;
      As[c][r] = A[(size_t)(bm * BM + r) * Kd + k0 + c];
    }
#pragma unroll
    for (int i = 0; i < 4; i++) {  // B tile 16x64 -> Bs[k][n]
      int linear = tid + i * 256;
      int r = linear >> 6, c = linear & 63;
      Bs[r][c] = B[(size_t)(k0 + r) * N + bn * BN + c];
    }
    __syncthreads();
#pragma unroll
    for (int kk = 0; kk < BK; kk++) {
      float a[4], b[4];
#pragma unroll
      for (int i = 0; i < 4; i++) a[i] = As[kk][ty * 4 + i];
#pragma unroll
      for (int j = 0; j < 4; j++) b[j] = Bs[kk][tx * 4 + j];
#pragma unroll
      for (int i = 0; i < 4; i++)
#pragma unroll
        for (int j = 0; j < 4; j++) acc[i][j] += a[i] * b[j];
    }
    __syncthreads();
  }

#pragma unroll
  for (int i = 0; i < 4; i++) {
    int m = bm * BM + ty * 4 + i;
#pragma unroll
    for (int j = 0; j < 4; j++) {
      int n = bn * BN + tx * 4 + j;
      float v = acc[i][j] + bias[n];
      if (mode == 1) v = 0.5f * v * (1.0f + erff(v * 0.70710678118f));
      else if (mode == 2) v += res[(size_t)m * N + n];
      C[(size_t)m * N + n] = v;
    }
  }
}

// ---------------- Attention: one wave per (query, head) -------------------
__global__ __launch_bounds__(64) void attn_kernel(
    const float* __restrict__ Q, const float* __restrict__ K,
    const float* __restrict__ V, float* __restrict__ out) {
  int q = blockIdx.x, h = blockIdx.y;
  int lane = threadIdx.x;  // 0..63
  __shared__ float sc[T_SEQ];
  __shared__ float qrow[HEAD_DIM];

  qrow[lane] = Q[(size_t)q * D_MODEL + h * HEAD_DIM + lane];
  __syncthreads();

  float slope = exp2f(-0.5f * (float)(h + 1));  // 2^(-8*(h+1)/16)
  int nk = q + 1;

  float lmax = -INFINITY;
  for (int k = lane; k < nk; k += 64) {
    const float* kr = K + (size_t)k * D_MODEL + h * HEAD_DIM;
    float s = 0.f;
#pragma unroll
    for (int d = 0; d < HEAD_DIM; d++) s += qrow[d] * kr[d];
    s = s * 0.125f + slope * (float)(k - q);  // /sqrt(64) + alibi (k<=q so k-q<=0)
    sc[k] = s;
    lmax = fmaxf(lmax, s);
  }
  for (int o = 32; o > 0; o >>= 1) lmax = fmaxf(lmax, __shfl_xor(lmax, o, 64));

  float lsum = 0.f;
  for (int k = lane; k < nk; k += 64) {
    float p = __expf(sc[k] - lmax);
    sc[k] = p;
    lsum += p;
  }
  for (int o = 32; o > 0; o >>= 1) lsum += __shfl_xor(lsum, o, 64);
  __syncthreads();

  // lane = output dim d; V reads coalesced across lanes
  float acc = 0.f;
  for (int k = 0; k < nk; k++)
    acc += sc[k] * V[(size_t)k * D_MODEL + h * HEAD_DIM + lane];
  out[(size_t)q * D_MODEL + h * HEAD_DIM + lane] = acc / lsum;
}

extern "C" void kernel_launch(void* const* d_in, const int* in_sizes, int n_in,
                              void* d_out, int out_size, void* d_ws, size_t ws_size,
                              hipStream_t stream) {
  const float* x   = (const float*)d_in[0];
  // d_in[1] causal_mask, d_in[2] alibi_bias: computed analytically, unused
  const float* wq  = (const float*)d_in[3];
  const float* bq  = (const float*)d_in[4];
  const float* wk  = (const float*)d_in[5];
  const float* bk  = (const float*)d_in[6];
  const float* wv  = (const float*)d_in[7];
  const float* bv  = (const float*)d_in[8];
  const float* wo  = (const float*)d_in[9];
  const float* bo  = (const float*)d_in[10];
  const float* w1  = (const float*)d_in[11];
  const float* b1  = (const float*)d_in[12];
  const float* w2  = (const float*)d_in[13];
  const float* b2  = (const float*)d_in[14];
  const float* g1  = (const float*)d_in[15];
  const float* be1 = (const float*)d_in[16];
  const float* g2  = (const float*)d_in[17];
  const float* be2 = (const float*)d_in[18];
  float* out = (float*)d_out;

  const size_t TD = (size_t)T_SEQ * D_MODEL;      // 2M floats
  float* ws = (float*)d_ws;
  float* xn       = ws;            // 2M
  float* Qb       = ws + 2 * TD;   // 2M
  float* Kb       = ws + 4 * TD / 2;  // careful: use explicit offsets below
  // explicit layout (floats):
  xn            = ws + 0 * TD;
  Qb            = ws + 1 * TD;
  float* Kbuf   = ws + 2 * TD;
  float* Vbuf   = ws + 3 * TD;
  float* attn_o = ws + 4 * TD;
  float* x1     = ws + 5 * TD;
  float* hbuf   = ws + 6 * TD;     // 2048*4096 = 4*TD floats -> total 10*TD = 80 MB

  dim3 blk256(256);

  // LN1
  ln_kernel<<<T_SEQ, blk256, 0, stream>>>(x, g1, be1, xn, D_MODEL);

  // Q, K, V projections
  dim3 gproj(D_MODEL / BN, T_SEQ / BM);
  gemm_kernel<<<gproj, blk256, 0, stream>>>(xn, wq, bq, nullptr, Qb,   T_SEQ, D_MODEL, D_MODEL, 0);
  gemm_kernel<<<gproj, blk256, 0, stream>>>(xn, wk, bk, nullptr, Kbuf, T_SEQ, D_MODEL, D_MODEL, 0);
  gemm_kernel<<<gproj, blk256, 0, stream>>>(xn, wv, bv, nullptr, Vbuf, T_SEQ, D_MODEL, D_MODEL, 0);

  // Attention
  dim3 gattn(T_SEQ, N_HEADS);
  attn_kernel<<<gattn, dim3(64), 0, stream>>>(Qb, Kbuf, Vbuf, attn_o);

  // Output projection + residual (x)
  gemm_kernel<<<gproj, blk256, 0, stream>>>(attn_o, wo, bo, x, x1, T_SEQ, D_MODEL, D_MODEL, 2);

  // LN2
  ln_kernel<<<T_SEQ, blk256, 0, stream>>>(x1, g2, be2, xn, D_MODEL);

  // FFN1 + GELU
  dim3 gffn1(FFN_DIM / BN, T_SEQ / BM);
  gemm_kernel<<<gffn1, blk256, 0, stream>>>(xn, w1, b1, nullptr, hbuf, T_SEQ, FFN_DIM, D_MODEL, 1);

  // FFN2 + residual (x1) -> out
  dim3 gffn2(D_MODEL / BN, T_SEQ / BM);
  gemm_kernel<<<gffn2, blk256, 0, stream>>>(hbuf, w2, b2, x1, out, T_SEQ, D_MODEL, FFN_DIM, 2);
}

// Round 2
// 1744.817 us; speedup vs baseline: 1.8644x; 1.8644x over previous
//
#include <hip/hip_runtime.h>
#include <hip/hip_bf16.h>
#include <math.h>

#define T_SEQ 2048
#define D_MODEL 1024
#define N_HEADS 16
#define HEAD_DIM 64
#define FFN_DIM 4096

typedef _Float16 halfx8 __attribute__((ext_vector_type(8)));
typedef float floatx4 __attribute__((ext_vector_type(4)));

// ---------------- LayerNorm: one block per row ----------------
__global__ __launch_bounds__(256) void ln_kernel(
    const float* __restrict__ x, const float* __restrict__ g,
    const float* __restrict__ b, float* __restrict__ y, int D) {
  int row = blockIdx.x;
  const float* xr = x + (size_t)row * D;
  float* yr = y + (size_t)row * D;
  int tid = threadIdx.x;
  int lid = tid & 63, wid = tid >> 6;
  __shared__ float red[8];

  float sum = 0.f;
  for (int i = tid; i < D; i += 256) sum += xr[i];
  for (int o = 32; o > 0; o >>= 1) sum += __shfl_down(sum, o, 64);
  if (lid == 0) red[wid] = sum;
  __syncthreads();
  if (tid == 0) { float t = 0; for (int i = 0; i < 4; i++) t += red[i]; red[0] = t; }
  __syncthreads();
  float mu = red[0] / D;
  __syncthreads();

  float vs = 0.f;
  for (int i = tid; i < D; i += 256) { float d = xr[i] - mu; vs += d * d; }
  for (int o = 32; o > 0; o >>= 1) vs += __shfl_down(vs, o, 64);
  if (lid == 0) red[wid] = vs;
  __syncthreads();
  if (tid == 0) { float t = 0; for (int i = 0; i < 4; i++) t += red[i]; red[0] = t; }
  __syncthreads();
  float rstd = rsqrtf(red[0] / D + 1e-5f);

  for (int i = tid; i < D; i += 256)
    yr[i] = (xr[i] - mu) * rstd * g[i] + b[i];
}

// ---------------- GEMM: C = A(MxK) @ B(KxN) + bias, fused epilogue --------
// mode 0: bias only; mode 1: bias + exact GELU; mode 2: bias + residual add
// mode 3: bias, store fp16 to Ch
#define BM 64
#define BN 64
#define BK 16
__global__ __launch_bounds__(256) void gemm_kernel(
    const float* __restrict__ A, const float* __restrict__ B,
    const float* __restrict__ bias, const float* __restrict__ res,
    float* __restrict__ C, _Float16* __restrict__ Ch,
    int M, int N, int Kd, int mode) {
  __shared__ float As[BK][BM + 1];
  __shared__ float Bs[BK][BN + 1];
  int tid = threadIdx.x;
  int bm = blockIdx.y, bn = blockIdx.x;
  int tx = tid & 15, ty = tid >> 4;
  float acc[4][4] = {};

  for (int k0 = 0; k0 < Kd; k0 += BK) {
#pragma unroll
    for (int i = 0; i < 4; i++) {  // A tile 64x16 -> As[k][m]
      int linear = tid + i * 256;
      int r = linear >> 4, c = linear & 15;
      As[c][r] = A[(size_t)(bm * BM + r) * Kd + k0 + c];
    }
#pragma unroll
    for (int i = 0; i < 4; i++) {  // B tile 16x64 -> Bs[k][n]
      int linear = tid + i * 256;
      int r = linear >> 6, c = linear & 63;
      Bs[r][c] = B[(size_t)(k0 + r) * N + bn * BN + c];
    }
    __syncthreads();
#pragma unroll
    for (int kk = 0; kk < BK; kk++) {
      float a[4], b[4];
#pragma unroll
      for (int i = 0; i < 4; i++) a[i] = As[kk][ty * 4 + i];
#pragma unroll
      for (int j = 0; j < 4; j++) b[j] = Bs[kk][tx * 4 + j];
#pragma unroll
      for (int i = 0; i < 4; i++)
#pragma unroll
        for (int j = 0; j < 4; j++) acc[i][j] += a[i] * b[j];
    }
    __syncthreads();
  }

#pragma unroll
  for (int i = 0; i < 4; i++) {
    int m = bm * BM + ty * 4 + i;
#pragma unroll
    for (int j = 0; j < 4; j++) {
      int n = bn * BN + tx * 4 + j;
      float v = acc[i][j] + bias[n];
      if (mode == 1) v = 0.5f * v * (1.0f + erff(v * 0.70710678118f));
      else if (mode == 2) v += res[(size_t)m * N + n];
      if (mode == 3) Ch[(size_t)m * N + n] = (_Float16)v;
      else C[(size_t)m * N + n] = v;
    }
  }
}

// ---------------- Flash attention: MFMA f16, online softmax ----------------
// Block = 256 threads (4 waves) handles (head, 64-query tile). Wave w owns
// q rows [q0+16w, q0+16w+16). Key tiles of 64 staged in LDS:
//   Ks[k][d]  natural, row stride 72 (pad 8) -> uniform bank spread for b128
//   Vt[d][k]  transposed; k swizzled in 8-elem granules: col=((k>>3)^(d>>3))*8+(k&7)
//   Ps[w][q][k]  per-wave P round-trip (C-layout -> A-layout)
#define LROW 72
__global__ __launch_bounds__(256) void flash_attn_kernel(
    const _Float16* __restrict__ Qg, const _Float16* __restrict__ Kg,
    const _Float16* __restrict__ Vg, float* __restrict__ out) {
  __shared__ _Float16 Ks[64][LROW];
  __shared__ _Float16 Vt[64][LROW];
  __shared__ _Float16 Ps[4][16][LROW];

  const int h = blockIdx.y;
  const int qt = blockIdx.x;
  const int q0 = qt * 64;
  const int tid = threadIdx.x;
  const int w = tid >> 6;
  const int lane = tid & 63;
  const int l16 = lane & 15;
  const int quad = lane >> 4;

  // Q fragments (A-layout: m=l16, k=quad*8+j), d halves 0..31 / 32..63
  const _Float16* qp = Qg + (size_t)(q0 + w * 16 + l16) * D_MODEL + h * HEAD_DIM;
  halfx8 qa0 = *(const halfx8*)(qp + quad * 8);
  halfx8 qa1 = *(const halfx8*)(qp + 32 + quad * 8);

  float m_i[4], l_i[4];
  floatx4 o_acc[4];
#pragma unroll
  for (int r = 0; r < 4; r++) { m_i[r] = -INFINITY; l_i[r] = 0.f; }
#pragma unroll
  for (int c = 0; c < 4; c++) o_acc[c] = (floatx4){0.f, 0.f, 0.f, 0.f};

  const float slope = exp2f(-0.5f * (float)(h + 1));
  const int row_base = q0 + w * 16 + quad * 4;  // +r gives global q row

  for (int t = 0; t <= qt; t++) {
    const int k0 = t * 64;
    __syncthreads();
    // ---- stage K tile (natural layout), 512 16B-chunks over 256 threads
#pragma unroll
    for (int it = 0; it < 2; it++) {
      int chunk = tid + it * 256;
      int kr = chunk >> 3, c8 = chunk & 7;
      *(halfx8*)(&Ks[kr][c8 * 8]) =
          *(const halfx8*)(Kg + (size_t)(k0 + kr) * D_MODEL + h * HEAD_DIM + c8 * 8);
    }
    // ---- stage V tile transposed + swizzled
#pragma unroll
    for (int it = 0; it < 2; it++) {
      int chunk = tid + it * 256;
      int kr = chunk >> 3, c8 = chunk & 7;
      halfx8 v = *(const halfx8*)(Vg + (size_t)(k0 + kr) * D_MODEL + h * HEAD_DIM + c8 * 8);
      int kg = kr >> 3, k7 = kr & 7;
#pragma unroll
      for (int j = 0; j < 8; j++)
        Vt[c8 * 8 + j][((kg ^ c8) << 3) + k7] = v[j];
    }
    __syncthreads();

    // ---- S = Q K^T  (4 key-subtiles of 16)
    float sc[4][4];
#pragma unroll
    for (int sub = 0; sub < 4; sub++) {
      halfx8 b0 = *(const halfx8*)(&Ks[sub * 16 + l16][quad * 8]);
      halfx8 b1 = *(const halfx8*)(&Ks[sub * 16 + l16][32 + quad * 8]);
      floatx4 acc = (floatx4){0.f, 0.f, 0.f, 0.f};
      acc = __builtin_amdgcn_mfma_f32_16x16x32_f16(qa0, b0, acc, 0, 0, 0);
      acc = __builtin_amdgcn_mfma_f32_16x16x32_f16(qa1, b1, acc, 0, 0, 0);
#pragma unroll
      for (int r = 0; r < 4; r++) sc[sub][r] = acc[r];
    }

    // ---- online softmax (rows = quad*4+r, cols = k0+sub*16+l16)
#pragma unroll
    for (int r = 0; r < 4; r++) {
      const int rg = row_base + r;
      float mx = m_i[r];
#pragma unroll
      for (int sub = 0; sub < 4; sub++) {
        int cg = k0 + sub * 16 + l16;
        float s = sc[sub][r] * 0.125f + slope * (float)(cg - rg);
        if (cg > rg) s = -1e30f;
        sc[sub][r] = s;
        mx = fmaxf(mx, s);
      }
      mx = fmaxf(mx, __shfl_xor(mx, 1, 64));
      mx = fmaxf(mx, __shfl_xor(mx, 2, 64));
      mx = fmaxf(mx, __shfl_xor(mx, 4, 64));
      mx = fmaxf(mx, __shfl_xor(mx, 8, 64));
      float alpha = __expf(m_i[r] - mx);
      m_i[r] = mx;
      float ls = 0.f;
#pragma unroll
      for (int sub = 0; sub < 4; sub++) {
        float p = __expf(sc[sub][r] - mx);
        ls += p;
        Ps[w][quad * 4 + r][sub * 16 + l16] = (_Float16)p;
      }
      ls += __shfl_xor(ls, 1, 64);
      ls += __shfl_xor(ls, 2, 64);
      ls += __shfl_xor(ls, 4, 64);
      ls += __shfl_xor(ls, 8, 64);
      l_i[r] = l_i[r] * alpha + ls;
#pragma unroll
      for (int c = 0; c < 4; c++) o_acc[c][r] *= alpha;
    }

    // ---- O += P V  (A=P from LDS, B=V^T swizzled; same-wave DS ordering)
#pragma unroll
    for (int kh = 0; kh < 2; kh++) {
      halfx8 pa = *(const halfx8*)(&Ps[w][l16][kh * 32 + quad * 8]);
      int kgrp = kh * 4 + quad;
#pragma unroll
      for (int c = 0; c < 4; c++) {
        int d = c * 16 + l16;
        halfx8 vb = *(const halfx8*)(&Vt[d][(kgrp ^ (d >> 3)) << 3]);
        o_acc[c] = __builtin_amdgcn_mfma_f32_16x16x32_f16(pa, vb, o_acc[c], 0, 0, 0);
      }
    }
  }

  // ---- epilogue: O / l
#pragma unroll
  for (int c = 0; c < 4; c++)
#pragma unroll
    for (int r = 0; r < 4; r++)
      out[(size_t)(row_base + r) * D_MODEL + h * HEAD_DIM + c * 16 + l16] =
          o_acc[c][r] / l_i[r];
}

extern "C" void kernel_launch(void* const* d_in, const int* in_sizes, int n_in,
                              void* d_out, int out_size, void* d_ws, size_t ws_size,
                              hipStream_t stream) {
  const float* x   = (const float*)d_in[0];
  const float* wq  = (const float*)d_in[3];
  const float* bq  = (const float*)d_in[4];
  const float* wk  = (const float*)d_in[5];
  const float* bk  = (const float*)d_in[6];
  const float* wv  = (const float*)d_in[7];
  const float* bv  = (const float*)d_in[8];
  const float* wo  = (const float*)d_in[9];
  const float* bo  = (const float*)d_in[10];
  const float* w1  = (const float*)d_in[11];
  const float* b1  = (const float*)d_in[12];
  const float* w2  = (const float*)d_in[13];
  const float* b2  = (const float*)d_in[14];
  const float* g1  = (const float*)d_in[15];
  const float* be1 = (const float*)d_in[16];
  const float* g2  = (const float*)d_in[17];
  const float* be2 = (const float*)d_in[18];
  float* out = (float*)d_out;

  const size_t TD = (size_t)T_SEQ * D_MODEL;  // 2M elements
  float* ws = (float*)d_ws;
  float* xn     = ws + 0 * TD;
  float* x1     = ws + 1 * TD;
  float* attn_o = ws + 2 * TD;
  float* hbuf   = ws + 3 * TD;               // 4*TD floats (2048x4096)
  _Float16* Qh = (_Float16*)(ws + 7 * TD);
  _Float16* Kh = Qh + TD;
  _Float16* Vh = Kh + TD;

  dim3 blk256(256);

  // LN1
  ln_kernel<<<T_SEQ, blk256, 0, stream>>>(x, g1, be1, xn, D_MODEL);

  // Q, K, V projections -> fp16
  dim3 gproj(D_MODEL / BN, T_SEQ / BM);
  gemm_kernel<<<gproj, blk256, 0, stream>>>(xn, wq, bq, nullptr, nullptr, Qh, T_SEQ, D_MODEL, D_MODEL, 3);
  gemm_kernel<<<gproj, blk256, 0, stream>>>(xn, wk, bk, nullptr, nullptr, Kh, T_SEQ, D_MODEL, D_MODEL, 3);
  gemm_kernel<<<gproj, blk256, 0, stream>>>(xn, wv, bv, nullptr, nullptr, Vh, T_SEQ, D_MODEL, D_MODEL, 3);

  // Flash attention
  dim3 gattn(T_SEQ / 64, N_HEADS);
  flash_attn_kernel<<<gattn, blk256, 0, stream>>>(Qh, Kh, Vh, attn_o);

  // Output projection + residual (x)
  gemm_kernel<<<gproj, blk256, 0, stream>>>(attn_o, wo, bo, x, x1, nullptr, T_SEQ, D_MODEL, D_MODEL, 2);

  // LN2
  ln_kernel<<<T_SEQ, blk256, 0, stream>>>(x1, g2, be2, xn, D_MODEL);

  // FFN1 + GELU
  dim3 gffn1(FFN_DIM / BN, T_SEQ / BM);
  gemm_kernel<<<gffn1, blk256, 0, stream>>>(xn, w1, b1, nullptr, hbuf, nullptr, T_SEQ, FFN_DIM, D_MODEL, 1);

  // FFN2 + residual (x1) -> out
  dim3 gffn2(D_MODEL / BN, T_SEQ / BM);
  gemm_kernel<<<gffn2, blk256, 0, stream>>>(hbuf, w2, b2, x1, out, nullptr, T_SEQ, D_MODEL, FFN_DIM, 2);
}

// Round 3
// 642.392 us; speedup vs baseline: 5.0640x; 2.7161x over previous
//
#include <hip/hip_runtime.h>
#include <hip/hip_bf16.h>
#include <math.h>

#define T_SEQ 2048
#define D_MODEL 1024
#define N_HEADS 16
#define HEAD_DIM 64
#define FFN_DIM 4096

typedef _Float16 halfx8 __attribute__((ext_vector_type(8)));
typedef _Float16 halfx4 __attribute__((ext_vector_type(4)));
typedef float floatx4 __attribute__((ext_vector_type(4)));

__device__ __forceinline__ void async_ld16(const _Float16* g, _Float16* l) {
  __builtin_amdgcn_global_load_lds(
      (const __attribute__((address_space(1))) unsigned int*)g,
      (__attribute__((address_space(3))) unsigned int*)l, 16, 0, 0);
}

// ---------------- LayerNorm: one block per row, fp16 out ----------------
__global__ __launch_bounds__(256) void ln_h_kernel(
    const float* __restrict__ x, const float* __restrict__ g,
    const float* __restrict__ b, _Float16* __restrict__ y, int D) {
  int row = blockIdx.x;
  const float* xr = x + (size_t)row * D;
  _Float16* yr = y + (size_t)row * D;
  int tid = threadIdx.x;
  int lid = tid & 63, wid = tid >> 6;
  __shared__ float red[8];

  float sum = 0.f;
  for (int i = tid; i < D; i += 256) sum += xr[i];
  for (int o = 32; o > 0; o >>= 1) sum += __shfl_down(sum, o, 64);
  if (lid == 0) red[wid] = sum;
  __syncthreads();
  if (tid == 0) { float t = 0; for (int i = 0; i < 4; i++) t += red[i]; red[0] = t; }
  __syncthreads();
  float mu = red[0] / D;
  __syncthreads();

  float vs = 0.f;
  for (int i = tid; i < D; i += 256) { float d = xr[i] - mu; vs += d * d; }
  for (int o = 32; o > 0; o >>= 1) vs += __shfl_down(vs, o, 64);
  if (lid == 0) red[wid] = vs;
  __syncthreads();
  if (tid == 0) { float t = 0; for (int i = 0; i < 4; i++) t += red[i]; red[0] = t; }
  __syncthreads();
  float rstd = rsqrtf(red[0] / D + 1e-5f);

  for (int i = tid; i < D; i += 256)
    yr[i] = (_Float16)((xr[i] - mu) * rstd * g[i] + b[i]);
}

// ------------- transpose + fp32->fp16 convert: out[n][k] = in[k][n] -------
__global__ __launch_bounds__(256) void transpose_h_kernel(
    const float* __restrict__ in, _Float16* __restrict__ out, int K, int N) {
  __shared__ float tile[32][33];
  int tk = blockIdx.y * 32, tn = blockIdx.x * 32;
  int tid = threadIdx.x;
  int r = tid >> 3;        // 0..31
  int c = (tid & 7) * 4;   // 0,4,..,28
  float4 v = *(const float4*)&in[(size_t)(tk + r) * N + tn + c];
  tile[r][c] = v.x; tile[r][c + 1] = v.y; tile[r][c + 2] = v.z; tile[r][c + 3] = v.w;
  __syncthreads();
  halfx4 o;
  o[0] = (_Float16)tile[c][r];
  o[1] = (_Float16)tile[c + 1][r];
  o[2] = (_Float16)tile[c + 2][r];
  o[3] = (_Float16)tile[c + 3][r];
  *(halfx4*)&out[(size_t)(tn + r) * K + tk + c] = o;
}

__global__ __launch_bounds__(256) void pack_bias_kernel(
    const float* __restrict__ bq, const float* __restrict__ bk,
    const float* __restrict__ bv, float* __restrict__ o) {
  int i = blockIdx.x * 256 + threadIdx.x;
  if (i < 1024) o[i] = bq[i];
  else if (i < 2048) o[i] = bk[i - 1024];
  else if (i < 3072) o[i] = bv[i - 2048];
}

// ---------------- MFMA f16 GEMM: C = A(MxK) @ Bt^T + bias ----------------
// Bt is N x K (pre-transposed weights). 128x128 tile, BK=32, 256 threads.
// MODE 0: bias -> fp16 Ch. MODE 1: bias + GELU -> fp16 Ch.
// MODE 2: bias + res(fp32) -> fp32 Cf.
template <int MODE>
__global__ __launch_bounds__(256) void hgemm_kernel(
    const _Float16* __restrict__ A, const _Float16* __restrict__ Bt,
    const float* __restrict__ bias, const float* __restrict__ res,
    float* __restrict__ Cf, _Float16* __restrict__ Ch,
    int M, int N, int K) {
  __shared__ _Float16 As[128][32];
  __shared__ _Float16 Bs[128][32];
  const int tid = threadIdx.x;
  const int w = tid >> 6, lane = tid & 63;
  const int l16 = lane & 15, quad = lane >> 4;
  const int m0 = blockIdx.y * 128, n0 = blockIdx.x * 128;
  const int wm = (w >> 1) * 64, wn = (w & 1) * 64;

  floatx4 acc[4][4];
#pragma unroll
  for (int i = 0; i < 4; i++)
#pragma unroll
    for (int j = 0; j < 4; j++) acc[i][j] = (floatx4){0.f, 0.f, 0.f, 0.f};

  // staging: wave w covers rows [w*32, w*32+32) of both tiles
  const int srow = lane >> 2;            // 0..15
  const int scol = (lane & 3) * 8;       // half offset
  const _Float16* Ag = A + (size_t)(m0 + w * 32 + srow) * K + scol;
  const _Float16* Bg = Bt + (size_t)(n0 + w * 32 + srow) * K + scol;
  _Float16* AsB = &As[w * 32][0];
  _Float16* BsB = &Bs[w * 32][0];

  for (int k0 = 0; k0 < K; k0 += 32) {
    async_ld16(Ag + k0, AsB);
    async_ld16(Ag + k0 + (size_t)16 * K, AsB + 16 * 32);
    async_ld16(Bg + k0, BsB);
    async_ld16(Bg + k0 + (size_t)16 * K, BsB + 16 * 32);
    __syncthreads();
    halfx8 af[4], bf[4];
#pragma unroll
    for (int mt = 0; mt < 4; mt++) af[mt] = *(const halfx8*)&As[wm + mt * 16 + l16][quad * 8];
#pragma unroll
    for (int nt = 0; nt < 4; nt++) bf[nt] = *(const halfx8*)&Bs[wn + nt * 16 + l16][quad * 8];
#pragma unroll
    for (int mt = 0; mt < 4; mt++)
#pragma unroll
      for (int nt = 0; nt < 4; nt++)
        acc[mt][nt] = __builtin_amdgcn_mfma_f32_16x16x32_f16(af[mt], bf[nt], acc[mt][nt], 0, 0, 0);
    __syncthreads();
  }

#pragma unroll
  for (int mt = 0; mt < 4; mt++) {
#pragma unroll
    for (int nt = 0; nt < 4; nt++) {
      int col = n0 + wn + nt * 16 + l16;
      float bv = bias[col];
#pragma unroll
      for (int r = 0; r < 4; r++) {
        int row = m0 + wm + mt * 16 + quad * 4 + r;
        float v = acc[mt][nt][r] + bv;
        if (MODE == 1) v = 0.5f * v * (1.0f + erff(v * 0.70710678118f));
        if (MODE == 2) {
          Cf[(size_t)row * N + col] = v + res[(size_t)row * N + col];
        } else {
          Ch[(size_t)row * N + col] = (_Float16)v;
        }
      }
    }
  }
}

// ---------------- Flash attention: MFMA f16, online softmax ----------------
// QKV fused buffer: row stride 3072; Q at +0, K at +1024, V at +2048.
#define LROW 72
#define QKV_STR 3072
__global__ __launch_bounds__(256) void flash_attn_kernel(
    const _Float16* __restrict__ QKV, _Float16* __restrict__ out) {
  __shared__ _Float16 Ks[64][LROW];
  __shared__ _Float16 Vt[64][LROW];
  __shared__ _Float16 Ps[4][16][LROW];

  const int h = blockIdx.y;
  const int qt = blockIdx.x;
  const int q0 = qt * 64;
  const int tid = threadIdx.x;
  const int w = tid >> 6;
  const int lane = tid & 63;
  const int l16 = lane & 15;
  const int quad = lane >> 4;

  const _Float16* Qg = QKV + h * HEAD_DIM;
  const _Float16* Kg = QKV + 1024 + h * HEAD_DIM;
  const _Float16* Vg = QKV + 2048 + h * HEAD_DIM;

  const _Float16* qp = Qg + (size_t)(q0 + w * 16 + l16) * QKV_STR;
  halfx8 qa0 = *(const halfx8*)(qp + quad * 8);
  halfx8 qa1 = *(const halfx8*)(qp + 32 + quad * 8);

  float m_i[4], l_i[4];
  floatx4 o_acc[4];
#pragma unroll
  for (int r = 0; r < 4; r++) { m_i[r] = -INFINITY; l_i[r] = 0.f; }
#pragma unroll
  for (int c = 0; c < 4; c++) o_acc[c] = (floatx4){0.f, 0.f, 0.f, 0.f};

  const float slope = exp2f(-0.5f * (float)(h + 1));
  const int row_base = q0 + w * 16 + quad * 4;

  for (int t = 0; t <= qt; t++) {
    const int k0 = t * 64;
    __syncthreads();
#pragma unroll
    for (int it = 0; it < 2; it++) {
      int chunk = tid + it * 256;
      int kr = chunk >> 3, c8 = chunk & 7;
      *(halfx8*)(&Ks[kr][c8 * 8]) =
          *(const halfx8*)(Kg + (size_t)(k0 + kr) * QKV_STR + c8 * 8);
    }
#pragma unroll
    for (int it = 0; it < 2; it++) {
      int chunk = tid + it * 256;
      int kr = chunk >> 3, c8 = chunk & 7;
      halfx8 v = *(const halfx8*)(Vg + (size_t)(k0 + kr) * QKV_STR + c8 * 8);
      int kg = kr >> 3, k7 = kr & 7;
#pragma unroll
      for (int j = 0; j < 8; j++)
        Vt[c8 * 8 + j][((kg ^ c8) << 3) + k7] = v[j];
    }
    __syncthreads();

    float sc[4][4];
#pragma unroll
    for (int sub = 0; sub < 4; sub++) {
      halfx8 b0 = *(const halfx8*)(&Ks[sub * 16 + l16][quad * 8]);
      halfx8 b1 = *(const halfx8*)(&Ks[sub * 16 + l16][32 + quad * 8]);
      floatx4 acc = (floatx4){0.f, 0.f, 0.f, 0.f};
      acc = __builtin_amdgcn_mfma_f32_16x16x32_f16(qa0, b0, acc, 0, 0, 0);
      acc = __builtin_amdgcn_mfma_f32_16x16x32_f16(qa1, b1, acc, 0, 0, 0);
#pragma unroll
      for (int r = 0; r < 4; r++) sc[sub][r] = acc[r];
    }

#pragma unroll
    for (int r = 0; r < 4; r++) {
      const int rg = row_base + r;
      float mx = m_i[r];
#pragma unroll
      for (int sub = 0; sub < 4; sub++) {
        int cg = k0 + sub * 16 + l16;
        float s = sc[sub][r] * 0.125f + slope * (float)(cg - rg);
        if (cg > rg) s = -1e30f;
        sc[sub][r] = s;
        mx = fmaxf(mx, s);
      }
      mx = fmaxf(mx, __shfl_xor(mx, 1, 64));
      mx = fmaxf(mx, __shfl_xor(mx, 2, 64));
      mx = fmaxf(mx, __shfl_xor(mx, 4, 64));
      mx = fmaxf(mx, __shfl_xor(mx, 8, 64));
      float alpha = __expf(m_i[r] - mx);
      m_i[r] = mx;
      float ls = 0.f;
#pragma unroll
      for (int sub = 0; sub < 4; sub++) {
        float p = __expf(sc[sub][r] - mx);
        ls += p;
        Ps[w][quad * 4 + r][sub * 16 + l16] = (_Float16)p;
      }
      ls += __shfl_xor(ls, 1, 64);
      ls += __shfl_xor(ls, 2, 64);
      ls += __shfl_xor(ls, 4, 64);
      ls += __shfl_xor(ls, 8, 64);
      l_i[r] = l_i[r] * alpha + ls;
#pragma unroll
      for (int c = 0; c < 4; c++) o_acc[c][r] *= alpha;
    }

#pragma unroll
    for (int kh = 0; kh < 2; kh++) {
      halfx8 pa = *(const halfx8*)(&Ps[w][l16][kh * 32 + quad * 8]);
      int kgrp = kh * 4 + quad;
#pragma unroll
      for (int c = 0; c < 4; c++) {
        int d = c * 16 + l16;
        halfx8 vb = *(const halfx8*)(&Vt[d][(kgrp ^ (d >> 3)) << 3]);
        o_acc[c] = __builtin_amdgcn_mfma_f32_16x16x32_f16(pa, vb, o_acc[c], 0, 0, 0);
      }
    }
  }

#pragma unroll
  for (int c = 0; c < 4; c++)
#pragma unroll
    for (int r = 0; r < 4; r++)
      out[(size_t)(row_base + r) * D_MODEL + h * HEAD_DIM + c * 16 + l16] =
          (_Float16)(o_acc[c][r] / l_i[r]);
}

extern "C" void kernel_launch(void* const* d_in, const int* in_sizes, int n_in,
                              void* d_out, int out_size, void* d_ws, size_t ws_size,
                              hipStream_t stream) {
  const float* x   = (const float*)d_in[0];
  const float* wq  = (const float*)d_in[3];
  const float* bq  = (const float*)d_in[4];
  const float* wk  = (const float*)d_in[5];
  const float* bk  = (const float*)d_in[6];
  const float* wv  = (const float*)d_in[7];
  const float* bv  = (const float*)d_in[8];
  const float* wo  = (const float*)d_in[9];
  const float* bo  = (const float*)d_in[10];
  const float* w1  = (const float*)d_in[11];
  const float* b1  = (const float*)d_in[12];
  const float* w2  = (const float*)d_in[13];
  const float* b2  = (const float*)d_in[14];
  const float* g1  = (const float*)d_in[15];
  const float* be1 = (const float*)d_in[16];
  const float* g2  = (const float*)d_in[17];
  const float* be2 = (const float*)d_in[18];
  float* out = (float*)d_out;

  const size_t TD = (size_t)T_SEQ * D_MODEL;  // 2M
  char* p = (char*)d_ws;
  float*    x1     = (float*)p;            p += TD * 4;            // 8 MB
  float*    bqkv   = (float*)p;            p += 4096 * 4;
  _Float16* xnh    = (_Float16*)p;         p += TD * 2;            // 4 MB
  _Float16* QKVh   = (_Float16*)p;         p += 3 * TD * 2;        // 12 MB
  _Float16* attnh  = (_Float16*)p;         p += TD * 2;            // 4 MB
  _Float16* hh     = (_Float16*)p;         p += 4 * TD * 2;        // 16 MB
  _Float16* Wqkvt  = (_Float16*)p;         p += 3 * 1024 * 1024 * 2;
  _Float16* Wot    = (_Float16*)p;         p += 1024 * 1024 * 2;
  _Float16* W1t    = (_Float16*)p;         p += (size_t)1024 * 4096 * 2;
  _Float16* W2t    = (_Float16*)p;         p += (size_t)4096 * 1024 * 2;

  dim3 blk(256);

  // weight transposes (fp32 -> fp16, out[n][k])
  transpose_h_kernel<<<dim3(32, 32), blk, 0, stream>>>(wq, Wqkvt, 1024, 1024);
  transpose_h_kernel<<<dim3(32, 32), blk, 0, stream>>>(wk, Wqkvt + 1024 * 1024, 1024, 1024);
  transpose_h_kernel<<<dim3(32, 32), blk, 0, stream>>>(wv, Wqkvt + 2 * 1024 * 1024, 1024, 1024);
  transpose_h_kernel<<<dim3(32, 32), blk, 0, stream>>>(wo, Wot, 1024, 1024);
  transpose_h_kernel<<<dim3(128, 32), blk, 0, stream>>>(w1, W1t, 1024, 4096);
  transpose_h_kernel<<<dim3(32, 128), blk, 0, stream>>>(w2, W2t, 4096, 1024);
  pack_bias_kernel<<<dim3(12), blk, 0, stream>>>(bq, bk, bv, bqkv);

  // LN1 -> fp16
  ln_h_kernel<<<T_SEQ, blk, 0, stream>>>(x, g1, be1, xnh, D_MODEL);

  // fused QKV projection: (2048x1024) @ (1024x3072)
  hgemm_kernel<0><<<dim3(3072 / 128, T_SEQ / 128), blk, 0, stream>>>(
      xnh, Wqkvt, bqkv, nullptr, nullptr, QKVh, T_SEQ, 3072, 1024);

  // flash attention
  flash_attn_kernel<<<dim3(T_SEQ / 64, N_HEADS), blk, 0, stream>>>(QKVh, attnh);

  // O-proj + residual(x) -> x1 (fp32)
  hgemm_kernel<2><<<dim3(1024 / 128, T_SEQ / 128), blk, 0, stream>>>(
      attnh, Wot, bo, x, x1, nullptr, T_SEQ, 1024, 1024);

  // LN2 -> fp16
  ln_h_kernel<<<T_SEQ, blk, 0, stream>>>(x1, g2, be2, xnh, D_MODEL);

  // FFN1 + GELU -> fp16
  hgemm_kernel<1><<<dim3(4096 / 128, T_SEQ / 128), blk, 0, stream>>>(
      xnh, W1t, b1, nullptr, nullptr, hh, T_SEQ, 4096, 1024);

  // FFN2 + residual(x1) -> out (fp32)
  hgemm_kernel<2><<<dim3(1024 / 128, T_SEQ / 128), blk, 0, stream>>>(
      hh, W2t, b2, x1, out, nullptr, T_SEQ, 1024, 4096);
}

// Round 4
// 599.205 us; speedup vs baseline: 5.4290x; 1.0721x over previous
//
#include <hip/hip_runtime.h>
#include <hip/hip_bf16.h>
#include <math.h>

#define T_SEQ 2048
#define D_MODEL 1024
#define N_HEADS 16
#define HEAD_DIM 64
#define FFN_DIM 4096

typedef _Float16 halfx8 __attribute__((ext_vector_type(8)));
typedef _Float16 halfx4 __attribute__((ext_vector_type(4)));
typedef float floatx4 __attribute__((ext_vector_type(4)));

__device__ __forceinline__ void async_ld16(const _Float16* g, _Float16* l) {
  __builtin_amdgcn_global_load_lds(
      (const __attribute__((address_space(1))) unsigned int*)g,
      (__attribute__((address_space(3))) unsigned int*)l, 16, 0, 0);
}

// ---------------- LayerNorm (D=1024 fixed): one block per row, fp16 out ----
__global__ __launch_bounds__(256) void ln_h_kernel(
    const float* __restrict__ x, const float* __restrict__ g,
    const float* __restrict__ b, _Float16* __restrict__ y) {
  int row = blockIdx.x;
  const float* xr = x + (size_t)row * D_MODEL;
  _Float16* yr = y + (size_t)row * D_MODEL;
  int tid = threadIdx.x;
  int lid = tid & 63, wid = tid >> 6;
  __shared__ float red[8];

  float4 v = *(const float4*)&xr[tid * 4];
  float sum = v.x + v.y + v.z + v.w;
  for (int o = 32; o > 0; o >>= 1) sum += __shfl_down(sum, o, 64);
  if (lid == 0) red[wid] = sum;
  __syncthreads();
  if (tid == 0) { float t = 0; for (int i = 0; i < 4; i++) t += red[i]; red[0] = t; }
  __syncthreads();
  float mu = red[0] * (1.0f / D_MODEL);
  __syncthreads();

  float dx = v.x - mu, dy = v.y - mu, dz = v.z - mu, dw = v.w - mu;
  float vs = dx * dx + dy * dy + dz * dz + dw * dw;
  for (int o = 32; o > 0; o >>= 1) vs += __shfl_down(vs, o, 64);
  if (lid == 0) red[wid] = vs;
  __syncthreads();
  if (tid == 0) { float t = 0; for (int i = 0; i < 4; i++) t += red[i]; red[0] = t; }
  __syncthreads();
  float rstd = rsqrtf(red[0] * (1.0f / D_MODEL) + 1e-5f);

  float4 gv = *(const float4*)&g[tid * 4];
  float4 bv = *(const float4*)&b[tid * 4];
  halfx4 o;
  o[0] = (_Float16)(dx * rstd * gv.x + bv.x);
  o[1] = (_Float16)(dy * rstd * gv.y + bv.y);
  o[2] = (_Float16)(dz * rstd * gv.z + bv.z);
  o[3] = (_Float16)(dw * rstd * gv.w + bv.w);
  *(halfx4*)&yr[tid * 4] = o;
}

// ------- fused prep: all 6 weight transposes (fp32->fp16 [n][k]) + bias ----
__global__ __launch_bounds__(256) void prep_kernel(
    const float* __restrict__ wq, const float* __restrict__ wk,
    const float* __restrict__ wv, const float* __restrict__ wo,
    const float* __restrict__ w1, const float* __restrict__ w2,
    const float* __restrict__ bq, const float* __restrict__ bk,
    const float* __restrict__ bv, _Float16* __restrict__ Wqkvt,
    _Float16* __restrict__ Wot, _Float16* __restrict__ W1t,
    _Float16* __restrict__ W2t, float* __restrict__ bqkv) {
  int bId = blockIdx.x;
  int tid = threadIdx.x;
  if (bId >= 12288) {  // bias pack: 12 blocks * 256 = 3072
    int i = (bId - 12288) * 256 + tid;
    if (i < 1024) bqkv[i] = bq[i];
    else if (i < 2048) bqkv[i] = bk[i - 1024];
    else bqkv[i] = bv[i - 2048];
    return;
  }
  const float* in; _Float16* outp; int K, N, t;
  if (bId < 1024)      { in = wq; outp = Wqkvt;                 K = 1024; N = 1024; t = bId; }
  else if (bId < 2048) { in = wk; outp = Wqkvt + 1024 * 1024;   K = 1024; N = 1024; t = bId - 1024; }
  else if (bId < 3072) { in = wv; outp = Wqkvt + 2 * 1024 * 1024; K = 1024; N = 1024; t = bId - 2048; }
  else if (bId < 4096) { in = wo; outp = Wot;                   K = 1024; N = 1024; t = bId - 3072; }
  else if (bId < 8192) { in = w1; outp = W1t;                   K = 1024; N = 4096; t = bId - 4096; }
  else                 { in = w2; outp = W2t;                   K = 4096; N = 1024; t = bId - 8192; }
  int ntn = N / 32;
  int tk = (t / ntn) * 32, tn = (t % ntn) * 32;

  __shared__ float tile[32][33];
  int r = tid >> 3, c = (tid & 7) * 4;
  float4 v = *(const float4*)&in[(size_t)(tk + r) * N + tn + c];
  tile[r][c] = v.x; tile[r][c + 1] = v.y; tile[r][c + 2] = v.z; tile[r][c + 3] = v.w;
  __syncthreads();
  halfx4 o;
  o[0] = (_Float16)tile[c][r];
  o[1] = (_Float16)tile[c + 1][r];
  o[2] = (_Float16)tile[c + 2][r];
  o[3] = (_Float16)tile[c + 3][r];
  *(halfx4*)&outp[(size_t)(tn + r) * K + tk + c] = o;
}

// ---------------- MFMA f16 GEMM: C = A(MxK) @ Bt^T + bias ----------------
// Bt is N x K (pre-transposed weights). BM_ x 128 tile, BK=32, 256 threads.
// MODE 0: bias -> fp16 Ch (stride N). MODE 1: bias + GELU -> fp16 Ch.
// MODE 2: bias + res(fp32) -> fp32 Cf.
// MODE 3 (QKV): col<2048 -> Ch row-major stride 2048 (Q|K);
//               col>=2048 -> V transposed: Vtg[(col-2048)*T_SEQ + row].
template <int MODE, int BM_>
__global__ __launch_bounds__(256) void hgemm_kernel(
    const _Float16* __restrict__ A, const _Float16* __restrict__ Bt,
    const float* __restrict__ bias, const float* __restrict__ res,
    float* __restrict__ Cf, _Float16* __restrict__ Ch,
    _Float16* __restrict__ Vtg, int M, int N, int K) {
  constexpr int TM = BM_ / 32;  // m-tiles per wave
  __shared__ _Float16 As[BM_][32];
  __shared__ _Float16 Bs[128][32];
  const int tid = threadIdx.x;
  const int w = tid >> 6, lane = tid & 63;
  const int l16 = lane & 15, quad = lane >> 4;
  const int m0 = blockIdx.y * BM_, n0 = blockIdx.x * 128;
  const int wm = (w >> 1) * (BM_ / 2), wn = (w & 1) * 64;

  floatx4 acc[TM][4];
#pragma unroll
  for (int i = 0; i < TM; i++)
#pragma unroll
    for (int j = 0; j < 4; j++) acc[i][j] = (floatx4){0.f, 0.f, 0.f, 0.f};

  const int srow = lane >> 2;       // 0..15
  const int scol = (lane & 3) * 8;  // half offset within BK
  const _Float16* Ag;
  _Float16* AsB;
  if (BM_ == 128) { Ag = A + (size_t)(m0 + w * 32 + srow) * K + scol; AsB = &As[w * 32][0]; }
  else            { Ag = A + (size_t)(m0 + w * 16 + srow) * K + scol; AsB = &As[w * 16][0]; }
  const _Float16* Bg = Bt + (size_t)(n0 + w * 32 + srow) * K + scol;
  _Float16* BsB = &Bs[w * 32][0];

  for (int k0 = 0; k0 < K; k0 += 32) {
    async_ld16(Ag + k0, AsB);
    if (BM_ == 128) async_ld16(Ag + k0 + (size_t)16 * K, AsB + 16 * 32);
    async_ld16(Bg + k0, BsB);
    async_ld16(Bg + k0 + (size_t)16 * K, BsB + 16 * 32);
    __syncthreads();
    halfx8 af[TM], bf[4];
#pragma unroll
    for (int mt = 0; mt < TM; mt++) af[mt] = *(const halfx8*)&As[wm + mt * 16 + l16][quad * 8];
#pragma unroll
    for (int nt = 0; nt < 4; nt++) bf[nt] = *(const halfx8*)&Bs[wn + nt * 16 + l16][quad * 8];
#pragma unroll
    for (int mt = 0; mt < TM; mt++)
#pragma unroll
      for (int nt = 0; nt < 4; nt++)
        acc[mt][nt] = __builtin_amdgcn_mfma_f32_16x16x32_f16(af[mt], bf[nt], acc[mt][nt], 0, 0, 0);
    __syncthreads();
  }

#pragma unroll
  for (int mt = 0; mt < TM; mt++) {
    int row0 = m0 + wm + mt * 16 + quad * 4;
#pragma unroll
    for (int nt = 0; nt < 4; nt++) {
      int col = n0 + wn + nt * 16 + l16;
      float bv = bias[col];
      float vv[4];
#pragma unroll
      for (int r = 0; r < 4; r++) {
        float v = acc[mt][nt][r] + bv;
        if (MODE == 1) v = 0.5f * v * (1.0f + erff(v * 0.70710678118f));
        vv[r] = v;
      }
      if (MODE == 2) {
#pragma unroll
        for (int r = 0; r < 4; r++)
          Cf[(size_t)(row0 + r) * N + col] = vv[r] + res[(size_t)(row0 + r) * N + col];
      } else if (MODE == 3) {
        if (col < 2048) {
#pragma unroll
          for (int r = 0; r < 4; r++)
            Ch[(size_t)(row0 + r) * 2048 + col] = (_Float16)vv[r];
        } else {
          halfx4 pk;
#pragma unroll
          for (int r = 0; r < 4; r++) pk[r] = (_Float16)vv[r];
          *(halfx4*)&Vtg[(size_t)(col - 2048) * T_SEQ + row0] = pk;
        }
      } else {
#pragma unroll
        for (int r = 0; r < 4; r++)
          Ch[(size_t)(row0 + r) * N + col] = (_Float16)vv[r];
      }
    }
  }
}

// ---------------- Flash attention: MFMA f16, online softmax ----------------
// QK buffer: [2048][2048] fp16, Q at cols 0..1023, K at 1024..2047.
// Vtg: V transposed [1024 d][2048 t] fp16.
#define LROW 72
__global__ __launch_bounds__(256) void flash_attn_kernel(
    const _Float16* __restrict__ QK, const _Float16* __restrict__ Vtg,
    _Float16* __restrict__ out) {
  __shared__ _Float16 Ks[64][LROW];
  __shared__ _Float16 Vt[64][LROW];
  __shared__ _Float16 Ps[4][16][LROW];

  const int h = blockIdx.y;
  const int qt = blockIdx.x;
  const int q0 = qt * 64;
  const int tid = threadIdx.x;
  const int w = tid >> 6;
  const int lane = tid & 63;
  const int l16 = lane & 15;
  const int quad = lane >> 4;

  const _Float16* Qg = QK + h * HEAD_DIM;
  const _Float16* Kg = QK + 1024 + h * HEAD_DIM;
  const _Float16* Vg = Vtg + (size_t)h * HEAD_DIM * T_SEQ;

  const _Float16* qp = Qg + (size_t)(q0 + w * 16 + l16) * 2048;
  halfx8 qa0 = *(const halfx8*)(qp + quad * 8);
  halfx8 qa1 = *(const halfx8*)(qp + 32 + quad * 8);

  float m_i[4], l_i[4];
  floatx4 o_acc[4];
#pragma unroll
  for (int r = 0; r < 4; r++) { m_i[r] = -INFINITY; l_i[r] = 0.f; }
#pragma unroll
  for (int c = 0; c < 4; c++) o_acc[c] = (floatx4){0.f, 0.f, 0.f, 0.f};

  // exp2-domain: s2 = qk*(0.125/ln2) + slope2*(k-q), p = exp2(s2 - m2)
  const float scale2 = 0.18033688f;                       // 0.125 * log2(e)
  const float slope2 = exp2f(-0.5f * (float)(h + 1)) * 1.44269504f;
  const int row_base = q0 + w * 16 + quad * 4;

  // per-thread staging coords: K rows kr/kr+32 (chunked 8 halves), V rows d/d+32
  const int kr = tid >> 3;   // 0..31
  const int c8 = tid & 7;    // granule
  halfx8 kpre0, kpre1, vpre0, vpre1;
#define PREFETCH(K0)                                                          \
  {                                                                           \
    kpre0 = *(const halfx8*)(Kg + (size_t)((K0) + kr) * 2048 + c8 * 8);       \
    kpre1 = *(const halfx8*)(Kg + (size_t)((K0) + kr + 32) * 2048 + c8 * 8);  \
    vpre0 = *(const halfx8*)(Vg + (size_t)kr * T_SEQ + (K0) + c8 * 8);        \
    vpre1 = *(const halfx8*)(Vg + (size_t)(kr + 32) * T_SEQ + (K0) + c8 * 8); \
  }
  PREFETCH(0)

  for (int t = 0; t <= qt; t++) {
    const int k0 = t * 64;
    __syncthreads();
    *(halfx8*)&Ks[kr][c8 * 8] = kpre0;
    *(halfx8*)&Ks[kr + 32][c8 * 8] = kpre1;
    *(halfx8*)&Vt[kr][((c8 ^ (kr >> 3)) & 7) * 8] = vpre0;
    *(halfx8*)&Vt[kr + 32][((c8 ^ ((kr + 32) >> 3)) & 7) * 8] = vpre1;
    __syncthreads();
    if (t < qt) PREFETCH(k0 + 64)

    // ---- S = Q K^T
    float sc[4][4];
#pragma unroll
    for (int sub = 0; sub < 4; sub++) {
      halfx8 b0 = *(const halfx8*)(&Ks[sub * 16 + l16][quad * 8]);
      halfx8 b1 = *(const halfx8*)(&Ks[sub * 16 + l16][32 + quad * 8]);
      floatx4 acc = (floatx4){0.f, 0.f, 0.f, 0.f};
      acc = __builtin_amdgcn_mfma_f32_16x16x32_f16(qa0, b0, acc, 0, 0, 0);
      acc = __builtin_amdgcn_mfma_f32_16x16x32_f16(qa1, b1, acc, 0, 0, 0);
#pragma unroll
      for (int r = 0; r < 4; r++) sc[sub][r] = acc[r];
    }

    // ---- online softmax (rows = quad*4+r, cols = k0+sub*16+l16)
#pragma unroll
    for (int r = 0; r < 4; r++) {
      const int rg = row_base + r;
      float mx = m_i[r];
#pragma unroll
      for (int sub = 0; sub < 4; sub++) {
        int cg = k0 + sub * 16 + l16;
        float s = sc[sub][r] * scale2 + slope2 * (float)(cg - rg);
        if (cg > rg) s = -1e30f;
        sc[sub][r] = s;
        mx = fmaxf(mx, s);
      }
      mx = fmaxf(mx, __shfl_xor(mx, 1, 64));
      mx = fmaxf(mx, __shfl_xor(mx, 2, 64));
      mx = fmaxf(mx, __shfl_xor(mx, 4, 64));
      mx = fmaxf(mx, __shfl_xor(mx, 8, 64));
      float alpha = exp2f(m_i[r] - mx);
      m_i[r] = mx;
      float ls = 0.f;
#pragma unroll
      for (int sub = 0; sub < 4; sub++) {
        float p = exp2f(sc[sub][r] - mx);
        ls += p;
        Ps[w][quad * 4 + r][sub * 16 + l16] = (_Float16)p;
      }
      ls += __shfl_xor(ls, 1, 64);
      ls += __shfl_xor(ls, 2, 64);
      ls += __shfl_xor(ls, 4, 64);
      ls += __shfl_xor(ls, 8, 64);
      l_i[r] = l_i[r] * alpha + ls;
#pragma unroll
      for (int c = 0; c < 4; c++) o_acc[c][r] *= alpha;
    }

    // ---- O += P V
#pragma unroll
    for (int kh = 0; kh < 2; kh++) {
      halfx8 pa = *(const halfx8*)(&Ps[w][l16][kh * 32 + quad * 8]);
      int kgrp = kh * 4 + quad;
#pragma unroll
      for (int c = 0; c < 4; c++) {
        int d = c * 16 + l16;
        halfx8 vb = *(const halfx8*)(&Vt[d][((kgrp ^ (d >> 3)) & 7) << 3]);
        o_acc[c] = __builtin_amdgcn_mfma_f32_16x16x32_f16(pa, vb, o_acc[c], 0, 0, 0);
      }
    }
  }

#pragma unroll
  for (int c = 0; c < 4; c++)
#pragma unroll
    for (int r = 0; r < 4; r++)
      out[(size_t)(row_base + r) * D_MODEL + h * HEAD_DIM + c * 16 + l16] =
          (_Float16)(o_acc[c][r] / l_i[r]);
}

extern "C" void kernel_launch(void* const* d_in, const int* in_sizes, int n_in,
                              void* d_out, int out_size, void* d_ws, size_t ws_size,
                              hipStream_t stream) {
  const float* x   = (const float*)d_in[0];
  const float* wq  = (const float*)d_in[3];
  const float* bq  = (const float*)d_in[4];
  const float* wk  = (const float*)d_in[5];
  const float* bk  = (const float*)d_in[6];
  const float* wv  = (const float*)d_in[7];
  const float* bv  = (const float*)d_in[8];
  const float* wo  = (const float*)d_in[9];
  const float* bo  = (const float*)d_in[10];
  const float* w1  = (const float*)d_in[11];
  const float* b1  = (const float*)d_in[12];
  const float* w2  = (const float*)d_in[13];
  const float* b2  = (const float*)d_in[14];
  const float* g1  = (const float*)d_in[15];
  const float* be1 = (const float*)d_in[16];
  const float* g2  = (const float*)d_in[17];
  const float* be2 = (const float*)d_in[18];
  float* out = (float*)d_out;

  const size_t TD = (size_t)T_SEQ * D_MODEL;  // 2M
  char* p = (char*)d_ws;
  float*    x1    = (float*)p;     p += TD * 4;                    // 8 MB
  float*    bqkv  = (float*)p;     p += 4096 * 4;
  _Float16* xnh   = (_Float16*)p;  p += TD * 2;                    // 4 MB
  _Float16* QKh   = (_Float16*)p;  p += (size_t)2048 * 2048 * 2;   // 8 MB
  _Float16* Vtg   = (_Float16*)p;  p += (size_t)1024 * 2048 * 2;   // 4 MB
  _Float16* attnh = (_Float16*)p;  p += TD * 2;                    // 4 MB
  _Float16* hh    = (_Float16*)p;  p += (size_t)2048 * 4096 * 2;   // 16 MB
  _Float16* Wqkvt = (_Float16*)p;  p += (size_t)3 * 1024 * 1024 * 2;
  _Float16* Wot   = (_Float16*)p;  p += (size_t)1024 * 1024 * 2;
  _Float16* W1t   = (_Float16*)p;  p += (size_t)1024 * 4096 * 2;
  _Float16* W2t   = (_Float16*)p;  p += (size_t)4096 * 1024 * 2;

  dim3 blk(256);

  // fused weight transposes + bias pack
  prep_kernel<<<dim3(12300), blk, 0, stream>>>(wq, wk, wv, wo, w1, w2, bq, bk, bv,
                                               Wqkvt, Wot, W1t, W2t, bqkv);

  // LN1 -> fp16
  ln_h_kernel<<<T_SEQ, blk, 0, stream>>>(x, g1, be1, xnh);

  // fused QKV projection: Q,K row-major [2048][2048]; V transposed [1024][2048]
  hgemm_kernel<3, 128><<<dim3(3072 / 128, T_SEQ / 128), blk, 0, stream>>>(
      xnh, Wqkvt, bqkv, nullptr, nullptr, QKh, Vtg, T_SEQ, 3072, 1024);

  // flash attention
  flash_attn_kernel<<<dim3(T_SEQ / 64, N_HEADS), blk, 0, stream>>>(QKh, Vtg, attnh);

  // O-proj + residual(x) -> x1 (fp32); BM=64 -> 256 blocks
  hgemm_kernel<2, 64><<<dim3(1024 / 128, T_SEQ / 64), blk, 0, stream>>>(
      attnh, Wot, bo, x, x1, nullptr, nullptr, T_SEQ, 1024, 1024);

  // LN2 -> fp16
  ln_h_kernel<<<T_SEQ, blk, 0, stream>>>(x1, g2, be2, xnh);

  // FFN1 + GELU -> fp16
  hgemm_kernel<1, 128><<<dim3(4096 / 128, T_SEQ / 128), blk, 0, stream>>>(
      xnh, W1t, b1, nullptr, nullptr, hh, nullptr, T_SEQ, 4096, 1024);

  // FFN2 + residual(x1) -> out (fp32); BM=64 -> 256 blocks
  hgemm_kernel<2, 64><<<dim3(1024 / 128, T_SEQ / 64), blk, 0, stream>>>(
      hh, W2t, b2, x1, out, nullptr, nullptr, T_SEQ, 1024, 4096);
}

// Round 5
// 568.789 us; speedup vs baseline: 5.7193x; 1.0535x over previous
//
#include <hip/hip_runtime.h>
#include <hip/hip_bf16.h>
#include <math.h>

#define T_SEQ 2048
#define D_MODEL 1024
#define N_HEADS 16
#define HEAD_DIM 64
#define FFN_DIM 4096

typedef _Float16 halfx8 __attribute__((ext_vector_type(8)));
typedef _Float16 halfx4 __attribute__((ext_vector_type(4)));
typedef float floatx4 __attribute__((ext_vector_type(4)));

__device__ __forceinline__ void async_ld16(const _Float16* g, _Float16* l) {
  __builtin_amdgcn_global_load_lds(
      (const __attribute__((address_space(1))) unsigned int*)g,
      (__attribute__((address_space(3))) unsigned int*)l, 16, 0, 0);
}

// ---------------- LayerNorm (D=1024 fixed): one block per row, fp16 out ----
__global__ __launch_bounds__(256) void ln_h_kernel(
    const float* __restrict__ x, const float* __restrict__ g,
    const float* __restrict__ b, _Float16* __restrict__ y) {
  int row = blockIdx.x;
  const float* xr = x + (size_t)row * D_MODEL;
  _Float16* yr = y + (size_t)row * D_MODEL;
  int tid = threadIdx.x;
  int lid = tid & 63, wid = tid >> 6;
  __shared__ float red[8];

  float4 v = *(const float4*)&xr[tid * 4];
  float sum = v.x + v.y + v.z + v.w;
  for (int o = 32; o > 0; o >>= 1) sum += __shfl_down(sum, o, 64);
  if (lid == 0) red[wid] = sum;
  __syncthreads();
  if (tid == 0) { float t = 0; for (int i = 0; i < 4; i++) t += red[i]; red[0] = t; }
  __syncthreads();
  float mu = red[0] * (1.0f / D_MODEL);
  __syncthreads();

  float dx = v.x - mu, dy = v.y - mu, dz = v.z - mu, dw = v.w - mu;
  float vs = dx * dx + dy * dy + dz * dz + dw * dw;
  for (int o = 32; o > 0; o >>= 1) vs += __shfl_down(vs, o, 64);
  if (lid == 0) red[wid] = vs;
  __syncthreads();
  if (tid == 0) { float t = 0; for (int i = 0; i < 4; i++) t += red[i]; red[0] = t; }
  __syncthreads();
  float rstd = rsqrtf(red[0] * (1.0f / D_MODEL) + 1e-5f);

  float4 gv = *(const float4*)&g[tid * 4];
  float4 bv = *(const float4*)&b[tid * 4];
  halfx4 o;
  o[0] = (_Float16)(dx * rstd * gv.x + bv.x);
  o[1] = (_Float16)(dy * rstd * gv.y + bv.y);
  o[2] = (_Float16)(dz * rstd * gv.z + bv.z);
  o[3] = (_Float16)(dw * rstd * gv.w + bv.w);
  *(halfx4*)&yr[tid * 4] = o;
}

// ------- fused prep: all 6 weight transposes (fp32->fp16 [n][k]) + bias ----
__global__ __launch_bounds__(256) void prep_kernel(
    const float* __restrict__ wq, const float* __restrict__ wk,
    const float* __restrict__ wv, const float* __restrict__ wo,
    const float* __restrict__ w1, const float* __restrict__ w2,
    const float* __restrict__ bq, const float* __restrict__ bk,
    const float* __restrict__ bv, _Float16* __restrict__ Wqkvt,
    _Float16* __restrict__ Wot, _Float16* __restrict__ W1t,
    _Float16* __restrict__ W2t, float* __restrict__ bqkv) {
  int bId = blockIdx.x;
  int tid = threadIdx.x;
  if (bId >= 12288) {  // bias pack
    int i = (bId - 12288) * 256 + tid;
    if (i < 1024) bqkv[i] = bq[i];
    else if (i < 2048) bqkv[i] = bk[i - 1024];
    else bqkv[i] = bv[i - 2048];
    return;
  }
  const float* in; _Float16* outp; int K, N, t;
  if (bId < 1024)      { in = wq; outp = Wqkvt;                 K = 1024; N = 1024; t = bId; }
  else if (bId < 2048) { in = wk; outp = Wqkvt + 1024 * 1024;   K = 1024; N = 1024; t = bId - 1024; }
  else if (bId < 3072) { in = wv; outp = Wqkvt + 2 * 1024 * 1024; K = 1024; N = 1024; t = bId - 2048; }
  else if (bId < 4096) { in = wo; outp = Wot;                   K = 1024; N = 1024; t = bId - 3072; }
  else if (bId < 8192) { in = w1; outp = W1t;                   K = 1024; N = 4096; t = bId - 4096; }
  else                 { in = w2; outp = W2t;                   K = 4096; N = 1024; t = bId - 8192; }
  int ntn = N / 32;
  int tk = (t / ntn) * 32, tn = (t % ntn) * 32;

  __shared__ float tile[32][33];
  int r = tid >> 3, c = (tid & 7) * 4;
  float4 v = *(const float4*)&in[(size_t)(tk + r) * N + tn + c];
  tile[r][c] = v.x; tile[r][c + 1] = v.y; tile[r][c + 2] = v.z; tile[r][c + 3] = v.w;
  __syncthreads();
  halfx4 o;
  o[0] = (_Float16)tile[c][r];
  o[1] = (_Float16)tile[c + 1][r];
  o[2] = (_Float16)tile[c + 2][r];
  o[3] = (_Float16)tile[c + 3][r];
  *(halfx4*)&outp[(size_t)(tn + r) * K + tk + c] = o;
}

// ---------------- MFMA f16 GEMM: C = A(MxK) @ Bt^T + bias ----------------
// Bt is N x K. BM x BN tile, BK=32, 256 threads, double-buffered LDS with
// ONE barrier per K-iter (async prefetch issued right after the barrier).
// LDS granule-swizzle: (row, global granule g) stored at slot g ^ ((row>>1)&3)
// -> async writes sequential, ds_read_b128 fragments 2-way (free).
// MODE 0: bias -> fp16 Ch. MODE 1: bias+GELU -> fp16 Ch.
// MODE 2: bias+res(fp32) -> fp32 Cf.
// MODE 3 (QKV): col<2048 -> Ch stride 2048 (Q|K); col>=2048 -> V^T to Vtg.
template <int MODE, int BM, int BN>
__global__ __launch_bounds__(256) void hgemm_kernel(
    const _Float16* __restrict__ A, const _Float16* __restrict__ Bt,
    const float* __restrict__ bias, const float* __restrict__ res,
    float* __restrict__ Cf, _Float16* __restrict__ Ch,
    _Float16* __restrict__ Vtg, int M, int N, int K) {
  constexpr int TM = BM / 32;
  constexpr int TN = BN / 32;
  constexpr int AR = BM / 64;  // async rounds for A tile
  constexpr int BR = BN / 64;
  __shared__ _Float16 As[2][BM][32];
  __shared__ _Float16 Bs[2][BN][32];
  const int tid = threadIdx.x;
  const int w = tid >> 6, lane = tid & 63;
  const int l16 = lane & 15, quad = lane >> 4;
  const int m0 = blockIdx.y * BM, n0 = blockIdx.x * BN;
  const int wm = (w >> 1) * (BM / 2), wn = (w & 1) * (BN / 2);

  floatx4 acc[TM][TN];
#pragma unroll
  for (int i = 0; i < TM; i++)
#pragma unroll
    for (int j = 0; j < TN; j++) acc[i][j] = (floatx4){0.f, 0.f, 0.f, 0.f};

  // staging coords (per thread, constant over K): round i covers local row
  // i*64 + w*16 + (lane>>2); lds slot granule lane&3; global granule gg.
  const int srow = w * 16 + (lane >> 2);
  const int gg = (lane & 3) ^ ((srow >> 1) & 3);
  const _Float16* Agp = A + (size_t)(m0 + srow) * K + gg * 8;
  const _Float16* Bgp = Bt + (size_t)(n0 + srow) * K + gg * 8;

  // fragment read granule (constant: wm/mt contributions vanish mod 4)
  const int colA = (quad ^ ((l16 >> 1) & 3)) * 8;

  const int NIT = K / 32;
#define HG_ISSUE(buf, k0)                                                     \
  {                                                                           \
    _Pragma("unroll") for (int i = 0; i < AR; i++)                            \
        async_ld16(Agp + (k0) + (size_t)i * 64 * K, &As[buf][i * 64 + w * 16][0]); \
    _Pragma("unroll") for (int i = 0; i < BR; i++)                            \
        async_ld16(Bgp + (k0) + (size_t)i * 64 * K, &Bs[buf][i * 64 + w * 16][0]); \
  }
  HG_ISSUE(0, 0)

  for (int it = 0; it < NIT; it++) {
    __syncthreads();  // drains async for buf (it&1); prior reads of other buf done
    if (it + 1 < NIT) HG_ISSUE((it + 1) & 1, (it + 1) * 32)
    const int buf = it & 1;
    halfx8 af[TM], bf[TN];
#pragma unroll
    for (int mt = 0; mt < TM; mt++)
      af[mt] = *(const halfx8*)&As[buf][wm + mt * 16 + l16][colA];
#pragma unroll
    for (int nt = 0; nt < TN; nt++)
      bf[nt] = *(const halfx8*)&Bs[buf][wn + nt * 16 + l16][colA];
#pragma unroll
    for (int mt = 0; mt < TM; mt++)
#pragma unroll
      for (int nt = 0; nt < TN; nt++)
        acc[mt][nt] = __builtin_amdgcn_mfma_f32_16x16x32_f16(af[mt], bf[nt], acc[mt][nt], 0, 0, 0);
  }

#pragma unroll
  for (int mt = 0; mt < TM; mt++) {
    int row0 = m0 + wm + mt * 16 + quad * 4;
#pragma unroll
    for (int nt = 0; nt < TN; nt++) {
      int col = n0 + wn + nt * 16 + l16;
      float bv = bias[col];
      float vv[4];
#pragma unroll
      for (int r = 0; r < 4; r++) {
        float v = acc[mt][nt][r] + bv;
        if (MODE == 1) v = 0.5f * v * (1.0f + erff(v * 0.70710678118f));
        vv[r] = v;
      }
      if (MODE == 2) {
#pragma unroll
        for (int r = 0; r < 4; r++)
          Cf[(size_t)(row0 + r) * N + col] = vv[r] + res[(size_t)(row0 + r) * N + col];
      } else if (MODE == 3) {
        if (col < 2048) {
#pragma unroll
          for (int r = 0; r < 4; r++)
            Ch[(size_t)(row0 + r) * 2048 + col] = (_Float16)vv[r];
        } else {
          halfx4 pk;
#pragma unroll
          for (int r = 0; r < 4; r++) pk[r] = (_Float16)vv[r];
          *(halfx4*)&Vtg[(size_t)(col - 2048) * T_SEQ + row0] = pk;
        }
      } else {
#pragma unroll
        for (int r = 0; r < 4; r++)
          Ch[(size_t)(row0 + r) * N + col] = (_Float16)vv[r];
      }
    }
  }
}

// ---------------- Flash attention: MFMA f16, online softmax ----------------
// QK buffer: [2048][2048] fp16, Q cols 0..1023, K cols 1024..2047.
// Vtg: V^T [1024 d][2048 t] fp16. K/V tiles staged via async global_load_lds
// into double-buffered LDS, XOR-granule swizzle (slot = g ^ (row&7)), one
// barrier per tile. Diagonal tile peeled (no causal select in main loop).
#define LROW 72
__global__ __launch_bounds__(256) void flash_attn_kernel(
    const _Float16* __restrict__ QK, const _Float16* __restrict__ Vtg,
    _Float16* __restrict__ out) {
  __shared__ _Float16 Ks[2][64][64];
  __shared__ _Float16 Vt[2][64][64];
  __shared__ _Float16 Ps[4][16][LROW];

  const int h = blockIdx.y;
  const int qt = 31 - blockIdx.x;  // LPT: heavy q-tiles dispatch first
  const int q0 = qt * 64;
  const int tid = threadIdx.x;
  const int w = tid >> 6;
  const int lane = tid & 63;
  const int l16 = lane & 15;
  const int quad = lane >> 4;

  const _Float16* Qg = QK + h * HEAD_DIM;
  const _Float16* Kg = QK + 1024 + h * HEAD_DIM;
  const _Float16* Vg = Vtg + (size_t)h * HEAD_DIM * T_SEQ;

  const _Float16* qp = Qg + (size_t)(q0 + w * 16 + l16) * 2048;
  halfx8 qa0 = *(const halfx8*)(qp + quad * 8);
  halfx8 qa1 = *(const halfx8*)(qp + 32 + quad * 8);

  float m_i[4], l_i[4];
  floatx4 o_acc[4];
#pragma unroll
  for (int r = 0; r < 4; r++) { m_i[r] = -INFINITY; l_i[r] = 0.f; }
#pragma unroll
  for (int c = 0; c < 4; c++) o_acc[c] = (floatx4){0.f, 0.f, 0.f, 0.f};

  const float scale2 = 0.18033688f;  // 0.125 * log2(e)
  const float slope2 = exp2f(-0.5f * (float)(h + 1)) * 1.44269504f;
  const int row_base = q0 + w * 16 + quad * 4;

  // staging coords: round i covers row i*32 + w*8 + (lane>>3), slot lane&7,
  // global granule gg = (lane&7) ^ ((lane>>3)&7)  (row&7 == (lane>>3)&7)
  const int sr = w * 8 + (lane >> 3);
  const int gg = (lane & 7) ^ ((lane >> 3) & 7);
  const _Float16* Kp = Kg + (size_t)sr * 2048 + gg * 8;
  const _Float16* Vp = Vg + (size_t)sr * 2048 + gg * 8;

  // fragment granule offsets (halves)
  const int m7 = l16 & 7;
  const int cK0 = (quad ^ m7) * 8;        // S-phase k-halves 0..31
  const int cK1 = cK0 ^ 32;               // k-halves 32..63
  const int cV0 = (quad ^ m7) * 8;        // PV kh=0 (kgrp = quad)
  const int cV1 = ((quad + 4) ^ m7) * 8;  // PV kh=1

#define FA_ISSUE(buf, k0)                                                      \
  {                                                                            \
    async_ld16(Kp + (size_t)(k0) * 2048, &Ks[buf][w * 8][0]);                  \
    async_ld16(Kp + (size_t)((k0) + 32) * 2048, &Ks[buf][32 + w * 8][0]);      \
    async_ld16(Vp + (k0), &Vt[buf][w * 8][0]);                                 \
    async_ld16(Vp + (size_t)32 * 2048 + (k0), &Vt[buf][32 + w * 8][0]);        \
  }
  FA_ISSUE(0, 0)

  for (int t = 0; t <= qt; t++) {
    const int k0 = t * 64;
    const int buf = t & 1;
    __syncthreads();  // async for buf done; prior reads of other buf done
    if (t < qt) FA_ISSUE(buf ^ 1, k0 + 64)

    // ---- S = Q K^T
    float sc[4][4];
#pragma unroll
    for (int sub = 0; sub < 4; sub++) {
      const _Float16* kr = &Ks[buf][sub * 16 + l16][0];
      halfx8 b0 = *(const halfx8*)(kr + cK0);
      halfx8 b1 = *(const halfx8*)(kr + cK1);
      floatx4 acc = (floatx4){0.f, 0.f, 0.f, 0.f};
      acc = __builtin_amdgcn_mfma_f32_16x16x32_f16(qa0, b0, acc, 0, 0, 0);
      acc = __builtin_amdgcn_mfma_f32_16x16x32_f16(qa1, b1, acc, 0, 0, 0);
#pragma unroll
      for (int r = 0; r < 4; r++) sc[sub][r] = acc[r];
    }

    // ---- online softmax (rows quad*4+r, cols k0+sub*16+l16)
    const bool diag = (t == qt);
#pragma unroll
    for (int r = 0; r < 4; r++) {
      const int rg = row_base + r;
      float mx = m_i[r];
#pragma unroll
      for (int sub = 0; sub < 4; sub++) {
        int cg = k0 + sub * 16 + l16;
        float s = sc[sub][r] * scale2 + slope2 * (float)(cg - rg);
        if (diag && cg > rg) s = -1e30f;
        sc[sub][r] = s;
        mx = fmaxf(mx, s);
      }
      mx = fmaxf(mx, __shfl_xor(mx, 1, 64));
      mx = fmaxf(mx, __shfl_xor(mx, 2, 64));
      mx = fmaxf(mx, __shfl_xor(mx, 4, 64));
      mx = fmaxf(mx, __shfl_xor(mx, 8, 64));
      float alpha = exp2f(m_i[r] - mx);
      m_i[r] = mx;
      float ls = 0.f;
#pragma unroll
      for (int sub = 0; sub < 4; sub++) {
        float p = exp2f(sc[sub][r] - mx);
        ls += p;
        Ps[w][quad * 4 + r][sub * 16 + l16] = (_Float16)p;
      }
      ls += __shfl_xor(ls, 1, 64);
      ls += __shfl_xor(ls, 2, 64);
      ls += __shfl_xor(ls, 4, 64);
      ls += __shfl_xor(ls, 8, 64);
      l_i[r] = l_i[r] * alpha + ls;
#pragma unroll
      for (int c = 0; c < 4; c++) o_acc[c][r] *= alpha;
    }

    // ---- O += P V
#pragma unroll
    for (int kh = 0; kh < 2; kh++) {
      halfx8 pa = *(const halfx8*)(&Ps[w][l16][kh * 32 + quad * 8]);
      const int cV = kh ? cV1 : cV0;
#pragma unroll
      for (int c = 0; c < 4; c++) {
        halfx8 vb = *(const halfx8*)(&Vt[buf][c * 16 + l16][cV]);
        o_acc[c] = __builtin_amdgcn_mfma_f32_16x16x32_f16(pa, vb, o_acc[c], 0, 0, 0);
      }
    }
  }

#pragma unroll
  for (int c = 0; c < 4; c++)
#pragma unroll
    for (int r = 0; r < 4; r++)
      out[(size_t)(row_base + r) * D_MODEL + h * HEAD_DIM + c * 16 + l16] =
          (_Float16)(o_acc[c][r] / l_i[r]);
}

extern "C" void kernel_launch(void* const* d_in, const int* in_sizes, int n_in,
                              void* d_out, int out_size, void* d_ws, size_t ws_size,
                              hipStream_t stream) {
  const float* x   = (const float*)d_in[0];
  const float* wq  = (const float*)d_in[3];
  const float* bq  = (const float*)d_in[4];
  const float* wk  = (const float*)d_in[5];
  const float* bk  = (const float*)d_in[6];
  const float* wv  = (const float*)d_in[7];
  const float* bv  = (const float*)d_in[8];
  const float* wo  = (const float*)d_in[9];
  const float* bo  = (const float*)d_in[10];
  const float* w1  = (const float*)d_in[11];
  const float* b1  = (const float*)d_in[12];
  const float* w2  = (const float*)d_in[13];
  const float* b2  = (const float*)d_in[14];
  const float* g1  = (const float*)d_in[15];
  const float* be1 = (const float*)d_in[16];
  const float* g2  = (const float*)d_in[17];
  const float* be2 = (const float*)d_in[18];
  float* out = (float*)d_out;

  const size_t TD = (size_t)T_SEQ * D_MODEL;  // 2M
  char* p = (char*)d_ws;
  float*    x1    = (float*)p;     p += TD * 4;
  float*    bqkv  = (float*)p;     p += 4096 * 4;
  _Float16* xnh   = (_Float16*)p;  p += TD * 2;
  _Float16* QKh   = (_Float16*)p;  p += (size_t)2048 * 2048 * 2;
  _Float16* Vtg   = (_Float16*)p;  p += (size_t)1024 * 2048 * 2;
  _Float16* attnh = (_Float16*)p;  p += TD * 2;
  _Float16* hh    = (_Float16*)p;  p += (size_t)2048 * 4096 * 2;
  _Float16* Wqkvt = (_Float16*)p;  p += (size_t)3 * 1024 * 1024 * 2;
  _Float16* Wot   = (_Float16*)p;  p += (size_t)1024 * 1024 * 2;
  _Float16* W1t   = (_Float16*)p;  p += (size_t)1024 * 4096 * 2;
  _Float16* W2t   = (_Float16*)p;  p += (size_t)4096 * 1024 * 2;

  dim3 blk(256);

  prep_kernel<<<dim3(12300), blk, 0, stream>>>(wq, wk, wv, wo, w1, w2, bq, bk, bv,
                                               Wqkvt, Wot, W1t, W2t, bqkv);

  ln_h_kernel<<<T_SEQ, blk, 0, stream>>>(x, g1, be1, xnh);

  // fused QKV: Q,K row-major [2048][2048]; V^T [1024][2048]. 768 blocks.
  hgemm_kernel<3, 64, 128><<<dim3(3072 / 128, T_SEQ / 64), blk, 0, stream>>>(
      xnh, Wqkvt, bqkv, nullptr, nullptr, QKh, Vtg, T_SEQ, 3072, 1024);

  flash_attn_kernel<<<dim3(T_SEQ / 64, N_HEADS), blk, 0, stream>>>(QKh, Vtg, attnh);

  // O-proj + residual(x) -> x1 (fp32). 512 blocks.
  hgemm_kernel<2, 64, 64><<<dim3(1024 / 64, T_SEQ / 64), blk, 0, stream>>>(
      attnh, Wot, bo, x, x1, nullptr, nullptr, T_SEQ, 1024, 1024);

  ln_h_kernel<<<T_SEQ, blk, 0, stream>>>(x1, g2, be2, xnh);

  // FFN1 + GELU -> fp16. 1024 blocks.
  hgemm_kernel<1, 64, 128><<<dim3(4096 / 128, T_SEQ / 64), blk, 0, stream>>>(
      xnh, W1t, b1, nullptr, nullptr, hh, nullptr, T_SEQ, 4096, 1024);

  // FFN2 + residual(x1) -> out (fp32). 512 blocks, K=4096.
  hgemm_kernel<2, 64, 64><<<dim3(1024 / 64, T_SEQ / 64), blk, 0, stream>>>(
      hh, W2t, b2, x1, out, nullptr, nullptr, T_SEQ, 1024, 4096);
}